// Round 17
// baseline (469.154 us; speedup 1.0000x reference)
//
#include <hip/hip_runtime.h>

#define N_NODES 50000
#define N_EDGES 800000
#define ETOT (N_EDGES + N_NODES)   // 850000
#define G_GRAPHS 256
#define F_IN 128
#define H1 12
#define D1 32
#define C1 (H1*D1)   // 384
#define C2 64
#define NEG 0.2f
#define SCAN_B 1024
#define NBLK_SCAN ((N_NODES + SCAN_B - 1)/SCAN_B)   // 49

using bf16x8  = __attribute__((ext_vector_type(8))) short;
using ushort8 = __attribute__((ext_vector_type(8))) unsigned short;
using f32x4   = __attribute__((ext_vector_type(4))) float;
using f32x2   = __attribute__((ext_vector_type(2))) float;

__device__ __forceinline__ float lrelu(float x){ return x > 0.f ? x : NEG*x; }
__device__ __forceinline__ unsigned short f2bf(float f){
  unsigned u = __float_as_uint(f);
  u += 0x7fffu + ((u >> 16) & 1u);
  return (unsigned short)(u >> 16);
}
__device__ __forceinline__ float bf2f(unsigned short h){
  return __uint_as_float(((unsigned)h) << 16);
}
// exp without max-subtraction; clamp is overflow guard only (never hit, |l|<=~8 here)
__device__ __forceinline__ float wexp(float l){ return __expf(fminf(l, 30.f)); }

// ---------- merged prep: cast x, transpose W1/W2, build wAb ----------
#define B_CAST ((N_NODES*F_IN/4 + 255)/256)   // 6250
#define B_W1   ((F_IN*C1 + 255)/256)          // 192
#define B_W2   ((C1*C2 + 255)/256)            // 96
#define B_WAB  ((32*F_IN + 255)/256)          // 16
__global__ void prep_kernel(const float* __restrict__ x, const float* __restrict__ W1,
    const float* __restrict__ W2, const float* __restrict__ att_src,
    const float* __restrict__ att_dst, unsigned short* __restrict__ xb,
    unsigned short* __restrict__ w1t, unsigned short* __restrict__ w2t,
    unsigned short* __restrict__ wAb){
  int b = blockIdx.x, tid = threadIdx.x;
  if (b < B_CAST){
    int base = (b*256 + tid)*4;
    if (base >= N_NODES*F_IN) return;
    float4 v = *(const float4*)(x + base);
    ushort4 o; o.x=f2bf(v.x); o.y=f2bf(v.y); o.z=f2bf(v.z); o.w=f2bf(v.w);
    *(ushort4*)(xb + base) = o;
  } else if (b < B_CAST + B_W1){
    int i = (b - B_CAST)*256 + tid;
    if (i >= F_IN*C1) return;
    int n = i / F_IN, k = i % F_IN;
    w1t[i] = f2bf(W1[(size_t)k*C1 + n]);
  } else if (b < B_CAST + B_W1 + B_W2){
    int i = (b - B_CAST - B_W1)*256 + tid;
    if (i >= C1*C2) return;
    int n = i / C1, k = i % C1;
    w2t[i] = f2bf(W2[(size_t)k*C2 + n]);
  } else {
    int i = (b - B_CAST - B_W1 - B_W2)*256 + tid;
    if (i >= 32*F_IN) return;
    int c = i >> 7, k = i & 127;
    float v = 0.f;
    if (c < 12){
      #pragma unroll
      for (int dd=0; dd<D1; ++dd) v += W1[(size_t)k*C1 + c*D1 + dd] * att_src[c*D1 + dd];
    } else if (c < 24){
      int h = c - 12;
      #pragma unroll
      for (int dd=0; dd<D1; ++dd) v += W1[(size_t)k*C1 + h*D1 + dd] * att_dst[h*D1 + dd];
    }
    wAb[i] = f2bf(v);
  }
}

// ---------- bf16 MFMA GEMM (logits): C[M][N] = A[M][K] @ Bt[N][K]^T ----------
template<int BM,int BN,int WM,int WN,bool F32OUT>
__global__ __launch_bounds__(256) void gemm_mfma(const unsigned short* __restrict__ A,
    const unsigned short* __restrict__ Bt, void* __restrict__ Cv,
    int M, int N, int K){
  constexpr int BK = 32;
  __shared__ unsigned short As2[4][BM][8];
  __shared__ unsigned short Bs2[4][BN][8];
  const int tid  = threadIdx.x;
  const int wid  = tid >> 6, lane = tid & 63;
  constexpr int NWX = BN / WN;
  const int wrow = (wid / NWX) * WM, wcol = (wid % NWX) * WN;
  constexpr int MR = WM/16, NR = WN/16;
  const int row0 = blockIdx.x * BM, col0 = blockIdx.y * BN;
  const int r = lane & 15, koct = lane >> 4;
  f32x4 acc[MR][NR];
  #pragma unroll
  for (int m=0;m<MR;m++)
    #pragma unroll
    for (int n=0;n<NR;n++) acc[m][n] = f32x4{0.f,0.f,0.f,0.f};

  for (int k0 = 0; k0 < K; k0 += BK){
    for (int s = tid; s < BM*8; s += 256){
      int rr = s >> 3, cc = (s & 7) * 4;
      int gr = row0 + rr;
      ushort4 v = (gr < M) ? *(const ushort4*)(A + (size_t)gr*K + k0 + cc)
                           : ushort4{0,0,0,0};
      *(ushort4*)(&As2[cc>>3][rr][cc&7]) = v;
    }
    for (int s = tid; s < BN*8; s += 256){
      int rr = s >> 3, cc = (s & 7) * 4;
      ushort4 v = *(const ushort4*)(Bt + (size_t)(col0+rr)*K + k0 + cc);
      *(ushort4*)(&Bs2[cc>>3][rr][cc&7]) = v;
    }
    __syncthreads();
    bf16x8 af[MR], bq[NR];
    #pragma unroll
    for (int m=0;m<MR;m++) af[m] = *(const bf16x8*)(&As2[koct][wrow + m*16 + r][0]);
    #pragma unroll
    for (int n=0;n<NR;n++) bq[n] = *(const bf16x8*)(&Bs2[koct][wcol + n*16 + r][0]);
    #pragma unroll
    for (int m=0;m<MR;m++)
      #pragma unroll
      for (int n=0;n<NR;n++)
        acc[m][n] = __builtin_amdgcn_mfma_f32_16x16x32_bf16(af[m], bq[n], acc[m][n], 0,0,0);
    __syncthreads();
  }
  #pragma unroll
  for (int m=0;m<MR;m++){
    #pragma unroll
    for (int rr=0; rr<4; rr++){
      int grow = row0 + wrow + m*16 + koct*4 + rr;
      if (grow < M){
        #pragma unroll
        for (int n=0;n<NR;n++){
          if constexpr (F32OUT)
            ((float*)Cv)[(size_t)grow*N + col0 + wcol + n*16 + r] = acc[m][n][rr];
          else
            ((unsigned short*)Cv)[(size_t)grow*N + col0 + wcol + n*16 + r] = f2bf(acc[m][n][rr]);
        }
      }
    }
  }
}

// ---------- CSR build ----------
#define EGRID ((ETOT + 255)/256)          // 3321
#define NGRID ((N_NODES + 255)/256)       // 196
__global__ void count_cnt_kernel(const int* __restrict__ ei, const int* __restrict__ batch,
                                 int* __restrict__ counts, int* __restrict__ cnt){
  if ((int)blockIdx.x < EGRID){
    int e = blockIdx.x*256 + threadIdx.x;
    if (e >= ETOT) return;
    int d = (e < N_EDGES) ? ei[N_EDGES + e] : (e - N_EDGES);
    atomicAdd(&counts[d], 1);
  } else {
    int n = (blockIdx.x - EGRID)*256 + threadIdx.x;
    if (n < N_NODES) atomicAdd(&cnt[batch[n]], 1);
  }
}
__global__ __launch_bounds__(SCAN_B) void scan_pass1(const int* __restrict__ counts,
    int* __restrict__ excl, int* __restrict__ bsum){
  __shared__ int sdata[SCAN_B];
  int i = blockIdx.x*SCAN_B + threadIdx.x;
  int v = (i < N_NODES) ? counts[i] : 0;
  sdata[threadIdx.x] = v;
  __syncthreads();
  for (int off=1; off<SCAN_B; off<<=1){
    int t = (threadIdx.x >= off) ? sdata[threadIdx.x-off] : 0;
    __syncthreads();
    sdata[threadIdx.x] += t;
    __syncthreads();
  }
  if (i < N_NODES) excl[i] = sdata[threadIdx.x] - v;
  if (threadIdx.x == SCAN_B-1) bsum[blockIdx.x] = sdata[SCAN_B-1];
}
__global__ void scan_pass3(int* __restrict__ rowptr, const int* __restrict__ bsum,
                           int* __restrict__ cursor){
  __shared__ int carry_s;
  int sblk = blockIdx.x >> 2;
  if (threadIdx.x == 0){
    int c = 0;
    for (int b=0; b<sblk; ++b) c += bsum[b];
    carry_s = c;
  }
  __syncthreads();
  int i = blockIdx.x*256 + (int)threadIdx.x;
  if (i < N_NODES){
    int r = rowptr[i] + carry_s;
    rowptr[i] = r; cursor[i] = r;
  }
  if (i == N_NODES) rowptr[N_NODES] = ETOT;
}
__global__ void scatter_kernel(const int* __restrict__ ei, int* __restrict__ cursor,
                               int* __restrict__ csr_src, int* __restrict__ csr_dst){
  int e = blockIdx.x*blockDim.x + threadIdx.x;
  if (e >= ETOT) return;
  int s, d;
  if (e < N_EDGES){ s = ei[e]; d = ei[N_EDGES + e]; } else { s = d = e - N_EDGES; }
  int slot = atomicAdd(&cursor[d], 1);
  csr_src[slot] = s;
  csr_dst[slot] = d;
}

// ---------- edge-parallel weight precompute: walpha[j][12] = bf16(exp(lrelu(aS+aD))) ----------
__global__ void wprep_kernel(const int* __restrict__ csr, const int* __restrict__ csrd,
                             const float* __restrict__ asd, unsigned short* __restrict__ walpha){
  int j = blockIdx.x*256 + threadIdx.x;
  if (j >= ETOT) return;
  int s = csr[j], d = csrd[j];
  float4 s0 = *(const float4*)(asd + (size_t)s*32);
  float4 s1 = *(const float4*)(asd + (size_t)s*32 + 4);
  float4 s2 = *(const float4*)(asd + (size_t)s*32 + 8);
  float4 d0 = *(const float4*)(asd + (size_t)d*32 + 12);
  float4 d1 = *(const float4*)(asd + (size_t)d*32 + 16);
  float4 d2 = *(const float4*)(asd + (size_t)d*32 + 20);
  float as[12] = {s0.x,s0.y,s0.z,s0.w, s1.x,s1.y,s1.z,s1.w, s2.x,s2.y,s2.z,s2.w};
  float ad[12] = {d0.x,d0.y,d0.z,d0.w, d1.x,d1.y,d1.z,d1.w, d2.x,d2.y,d2.z,d2.w};
  unsigned short wb[12];
  #pragma unroll
  for (int h=0;h<12;h++) wb[h] = f2bf(wexp(lrelu(as[h] + ad[h])));
  unsigned short* wp = walpha + (size_t)j*12;
  *(ushort4*)(wp)   = ushort4{wb[0],wb[1],wb[2],wb[3]};
  *(ushort4*)(wp+4) = ushort4{wb[4],wb[5],wb[6],wb[7]};
  *(ushort4*)(wp+8) = ushort4{wb[8],wb[9],wb[10],wb[11]};
}

// ---------- conv1 grand-fused: 32 lanes/dst, deep-pipelined gathers (depth 8),
//            packed FMA, chunk-32 staged w (zero-padded), + W1 MFMA + ReLU
//            + gemm2 partials + a2. out1 never materialized.
__global__ __launch_bounds__(512, 4) void agg1h_kernel(const int* __restrict__ rowptr,
    const int* __restrict__ csr, const unsigned short* __restrict__ xb,
    const unsigned short* __restrict__ walpha, const unsigned short* __restrict__ w1t,
    const unsigned short* __restrict__ w2t, const float* __restrict__ bias1,
    const float* __restrict__ att_src2, const float* __restrict__ att_dst2,
    unsigned short* __restrict__ h2, float* __restrict__ asrc2, float* __restrict__ adst2){
  constexpr int ROWE = 6*F_IN + 8;            // 776 ushorts, per-slot agg row (6 heads)
  constexpr int WROW = 32*12 + 4;             // 388 floats, per-slot weight row (chunk 32)
  constexpr int ROWR = 192 + 8;               // 200 ushorts, relu-out1 half-row
  __shared__ unsigned short agg[16*ROWE];     // 24832 B  (aliased: red at end)
  __shared__ float wlds[16][WROW];            // 24832 B  (aliased: reluLDS in epilogue)

  unsigned short* reluLDS = (unsigned short*)&wlds[0][0];   // 16 x ROWR ushorts = 6400 B
  float* red = (float*)&agg[0];                              // a2 reduce scratch

  const int tid  = threadIdx.x;
  const int wv   = tid >> 6;                  // wave 0..7
  const int lane = tid & 63;
  const int half = lane >> 5;                 // which dst of the wave's pair
  const int t32  = lane & 31;                 // lane within dst (4 feats each)
  const int base = lane & 32;                 // wave-lane base of this 32-lane group
  const int slot = wv*2 + half;               // 0..15 dst in block
  const int d    = blockIdx.x*16 + slot;
  const int r0 = rowptr[d], r1 = rowptr[d+1];

  f32x2 acc[12][2];
  #pragma unroll
  for (int h=0;h<12;h++){ acc[h][0] = f32x2{0.f,0.f}; acc[h][1] = f32x2{0.f,0.f}; }
  float ss[12];
  #pragma unroll
  for (int h=0;h<12;h++) ss[h] = 0.f;

  // ---- main loop: 32-edge chunks; ALL 32 lanes stage (w or zeros -> LDS) ----
  for (int c0 = r0; c0 < r1; c0 += 32){
    int nc = min(32, r1 - c0);
    int s_st = 0;
    if (t32 < nc){
      int j = c0 + t32;
      s_st = csr[j];
      const unsigned short* wp = walpha + (size_t)j*12;
      ushort4 u0 = *(const ushort4*)(wp);
      ushort4 u1 = *(const ushort4*)(wp+4);
      ushort4 u2 = *(const ushort4*)(wp+8);
      float w[12] = {bf2f(u0.x),bf2f(u0.y),bf2f(u0.z),bf2f(u0.w),
                     bf2f(u1.x),bf2f(u1.y),bf2f(u1.z),bf2f(u1.w),
                     bf2f(u2.x),bf2f(u2.y),bf2f(u2.z),bf2f(u2.w)};
      #pragma unroll
      for (int h=0;h<12;h++) ss[h] += w[h];
      *(float4*)(&wlds[slot][t32*12 + 0]) = float4{w[0],w[1],w[2],w[3]};
      *(float4*)(&wlds[slot][t32*12 + 4]) = float4{w[4],w[5],w[6],w[7]};
      *(float4*)(&wlds[slot][t32*12 + 8]) = float4{w[8],w[9],w[10],w[11]};
    } else {
      float4 z = {0.f,0.f,0.f,0.f};
      *(float4*)(&wlds[slot][t32*12 + 0]) = z;
      *(float4*)(&wlds[slot][t32*12 + 4]) = z;
      *(float4*)(&wlds[slot][t32*12 + 8]) = z;
    }
    __builtin_amdgcn_wave_barrier();

    #define XLOAD1(e) (*(const ushort4*)(xb + (size_t)__shfl(s_st, base + min((int)(e), 31))*F_IN + t32*4))
    #define PROC1(e, cx) { \
      float4 w0 = *(const float4*)(&wlds[slot][(e)*12 + 0]); \
      float4 w1 = *(const float4*)(&wlds[slot][(e)*12 + 4]); \
      float4 w2 = *(const float4*)(&wlds[slot][(e)*12 + 8]); \
      f32x2 x01 = {bf2f((cx).x), bf2f((cx).y)}; \
      f32x2 x23 = {bf2f((cx).z), bf2f((cx).w)}; \
      float wsc[12] = {w0.x,w0.y,w0.z,w0.w, w1.x,w1.y,w1.z,w1.w, w2.x,w2.y,w2.z,w2.w}; \
      _Pragma("unroll") \
      for (int h=0;h<12;h++){ f32x2 wb = {wsc[h],wsc[h]}; acc[h][0]+=wb*x01; acc[h][1]+=wb*x23; } }

    // prologue: two 4-edge batches in flight (depth 8)
    ushort4 A0 = XLOAD1(0), A1 = XLOAD1(1), A2 = XLOAD1(2), A3 = XLOAD1(3);
    ushort4 B0 = XLOAD1(4), B1 = XLOAD1(5), B2 = XLOAD1(6), B3 = XLOAD1(7);
    for (int e0 = 0; e0 < nc; e0 += 8){
      PROC1(e0+0, A0); PROC1(e0+1, A1); PROC1(e0+2, A2); PROC1(e0+3, A3);
      A0 = XLOAD1(e0+8);  A1 = XLOAD1(e0+9);  A2 = XLOAD1(e0+10); A3 = XLOAD1(e0+11);
      PROC1(e0+4, B0); PROC1(e0+5, B1); PROC1(e0+6, B2); PROC1(e0+7, B3);
      B0 = XLOAD1(e0+12); B1 = XLOAD1(e0+13); B2 = XLOAD1(e0+14); B3 = XLOAD1(e0+15);
    }
    #undef XLOAD1
    #undef PROC1
    __builtin_amdgcn_wave_barrier();
  }

  // reduce ss over 32-lane group; normalize factors
  #pragma unroll
  for (int h=0;h<12;h++){
    #pragma unroll
    for (int off=16; off; off>>=1) ss[h] += __shfl_xor(ss[h], off);
  }
  float inv[12];
  #pragma unroll
  for (int h=0;h<12;h++) inv[h] = 1.f / ss[h];

  // ---- epilogue: per 6-head half: agg->LDS, W1-MFMA + bias + ReLU -> reluLDS,
  //      then partial gemm2 (K=192) accumulating h2 in regs ----
  const int er = lane & 15, eq = lane >> 4;
  f32x4 h2acc = {0.f,0.f,0.f,0.f};
  #pragma unroll
  for (int hf = 0; hf < 2; ++hf){
    __syncthreads();   // main loop done (hf=0) / prev half's reluLDS+agg reads done (hf=1)
    #pragma unroll
    for (int h = 0; h < 6; ++h){
      int hh = hf*6 + h;
      ushort4 v;
      v.x = f2bf(acc[hh][0][0]*inv[hh]); v.y = f2bf(acc[hh][0][1]*inv[hh]);
      v.z = f2bf(acc[hh][1][0]*inv[hh]); v.w = f2bf(acc[hh][1][1]*inv[hh]);
      *(ushort4*)(&agg[slot*ROWE + h*F_IN + t32*4]) = v;
    }
    __syncthreads();
    // W1 transform: 12 tiles (192 cols this half) over 8 waves
    for (int tt = wv; tt < 12; tt += 8){
      int h = tt >> 1, nb = tt & 1;
      int hh = hf*6 + h;
      f32x4 c = {0.f,0.f,0.f,0.f};
      #pragma unroll
      for (int kk=0; kk<4; ++kk){
        bf16x8 af = *(const bf16x8*)(&agg[er*ROWE + h*F_IN + kk*32 + eq*8]);
        bf16x8 bq = *(const bf16x8*)(w1t + (size_t)(hh*32 + nb*16 + er)*F_IN + kk*32 + eq*8);
        c = __builtin_amdgcn_mfma_f32_16x16x32_bf16(af, bq, c, 0,0,0);
      }
      int lcol = tt*16 + er;                    // local col within half (0..191)
      float bv = bias1[hf*192 + lcol];
      #pragma unroll
      for (int rr=0; rr<4; ++rr){
        int row = eq*4 + rr;                    // dst row 0..15
        reluLDS[row*ROWR + lcol] = f2bf(fmaxf(c[rr] + bv, 0.f));
      }
    }
    __syncthreads();
    // partial gemm2: waves 0..3 own h2 cols [wv*16, wv*16+16), K=192 this half
    if (wv < 4){
      #pragma unroll
      for (int kk=0; kk<6; ++kk){
        bf16x8 af = *(const bf16x8*)(&reluLDS[er*ROWR + kk*32 + eq*8]);
        bf16x8 bq = *(const bf16x8*)(w2t + (size_t)(wv*16 + er)*C1 + hf*192 + kk*32 + eq*8);
        h2acc = __builtin_amdgcn_mfma_f32_16x16x32_bf16(af, bq, h2acc, 0,0,0);
      }
    }
  }
  __syncthreads();   // reluLDS/agg reads done; agg region reusable as red

  // ---- write h2 (bf16) + a2 dots (waves 0..3) ----
  if (wv < 4){
    float attS = att_src2[wv*16 + er];
    float attD = att_dst2[wv*16 + er];
    float psum[4], pdum[4];
    #pragma unroll
    for (int rr=0; rr<4; ++rr){
      int row = eq*4 + rr;
      int gn = blockIdx.x*16 + row;
      h2[(size_t)gn*C2 + wv*16 + er] = f2bf(h2acc[rr]);
      psum[rr] = h2acc[rr]*attS;
      pdum[rr] = h2acc[rr]*attD;
    }
    #pragma unroll
    for (int rr=0; rr<4; ++rr){
      #pragma unroll
      for (int off=8; off; off>>=1){
        psum[rr] += __shfl_xor(psum[rr], off);
        pdum[rr] += __shfl_xor(pdum[rr], off);
      }
    }
    if (er == 0){
      #pragma unroll
      for (int rr=0; rr<4; ++rr){
        int row = eq*4 + rr;
        red[(wv*16 + row)*2 + 0] = psum[rr];
        red[(wv*16 + row)*2 + 1] = pdum[rr];
      }
    }
  }
  __syncthreads();
  if (tid < 32){
    int row = tid >> 1, which = tid & 1;
    float v = red[row*2+which] + red[(16+row)*2+which] + red[(32+row)*2+which] + red[(48+row)*2+which];
    int gn = blockIdx.x*16 + row;
    if (which == 0) asrc2[gn] = v; else adst2[gn] = v;
  }
}

// ---------- conv2: no-max softmax + aggregation + pool atomics (deep pipeline) ----------
__global__ __launch_bounds__(256) void agg2s_kernel(const int* __restrict__ rowptr,
    const int* __restrict__ csr, const unsigned short* __restrict__ h2,
    const float* __restrict__ asrc, const float* __restrict__ adst,
    const float* __restrict__ bias, const int* __restrict__ batch,
    float* __restrict__ pool){
  const int tid  = threadIdx.x;
  const int slot = tid >> 4;
  const int t16  = tid & 15;
  const int base = ((tid & 63) >> 4) * 16;
  const int d    = blockIdx.x*16 + slot;
  const int r0 = rowptr[d], r1 = rowptr[d+1];
  const float ad = adst[d];

  float ssp = 0.f;
  f32x2 a01 = {0.f,0.f}, a23 = {0.f,0.f};

  for (int c0 = r0; c0 < r1; c0 += 16){
    int nc = min(16, r1 - c0);
    int s_st = 0; float w_st = 0.f;
    if (t16 < nc){
      s_st = csr[c0 + t16];
      w_st = wexp(lrelu(asrc[s_st] + ad));
      ssp += w_st;
    }

    #define XLOAD2(e) (*(const ushort4*)(h2 + (size_t)__shfl(s_st, base + min((int)(e), 15))*C2 + t16*4))
    #define PROC2(e, cx) { \
      float w = __shfl(w_st, base + min((int)(e), 15)); \
      w = ((e) < nc) ? w : 0.f; \
      f32x2 wb = {w, w}; \
      f32x2 x01 = {bf2f((cx).x), bf2f((cx).y)}; \
      f32x2 x23 = {bf2f((cx).z), bf2f((cx).w)}; \
      a01 += wb * x01; \
      a23 += wb * x23; }

    ushort4 A0 = XLOAD2(0), A1 = XLOAD2(1), A2 = XLOAD2(2), A3 = XLOAD2(3);
    ushort4 B0 = XLOAD2(4), B1 = XLOAD2(5), B2 = XLOAD2(6), B3 = XLOAD2(7);
    for (int e0 = 0; e0 < nc; e0 += 8){
      PROC2(e0+0, A0); PROC2(e0+1, A1); PROC2(e0+2, A2); PROC2(e0+3, A3);
      A0 = XLOAD2(e0+8);  A1 = XLOAD2(e0+9);  A2 = XLOAD2(e0+10); A3 = XLOAD2(e0+11);
      PROC2(e0+4, B0); PROC2(e0+5, B1); PROC2(e0+6, B2); PROC2(e0+7, B3);
      B0 = XLOAD2(e0+12); B1 = XLOAD2(e0+13); B2 = XLOAD2(e0+14); B3 = XLOAD2(e0+15);
    }
    #undef XLOAD2
    #undef PROC2
  }
  #pragma unroll
  for (int off=8; off; off>>=1) ssp += __shfl_xor(ssp, off);
  float inv = 1.f / ssp;
  int g = batch[d];
  int fb = t16*4;
  atomicAdd(&pool[g*C2 + fb+0], a01[0]*inv + bias[fb+0]);
  atomicAdd(&pool[g*C2 + fb+1], a01[1]*inv + bias[fb+1]);
  atomicAdd(&pool[g*C2 + fb+2], a23[0]*inv + bias[fb+2]);
  atomicAdd(&pool[g*C2 + fb+3], a23[1]*inv + bias[fb+3]);
}

__global__ void finalize_kernel(const float* __restrict__ sums, const int* __restrict__ cnt,
                                float* __restrict__ out){
  int i = blockIdx.x*blockDim.x + threadIdx.x;
  if (i >= G_GRAPHS*C2) return;
  int g = i >> 6;
  out[i] = sums[i] / fmaxf((float)cnt[g], 1.f);
}

// ---------- launch ----------
extern "C" void kernel_launch(void* const* d_in, const int* in_sizes, int n_in,
                              void* d_out, int out_size, void* d_ws, size_t ws_size,
                              hipStream_t stream) {
  const float* x        = (const float*)d_in[0];
  const int*   ei       = (const int*)  d_in[1];
  const int*   batch    = (const int*)  d_in[2];
  const float* W1       = (const float*)d_in[3];
  const float* att_src1 = (const float*)d_in[4];
  const float* att_dst1 = (const float*)d_in[5];
  const float* bias1    = (const float*)d_in[6];
  const float* W2       = (const float*)d_in[7];
  const float* att_src2 = (const float*)d_in[8];
  const float* att_dst2 = (const float*)d_in[9];
  const float* bias2    = (const float*)d_in[10];
  float* out = (float*)d_out;

  char* ws = (char*)d_ws;
  size_t o = 0;
  auto alloc = [&](size_t bytes)->size_t{ size_t r=o; o=(o+bytes+255)&~(size_t)255; return r; };

  size_t xb_o     = alloc((size_t)N_NODES*F_IN*2);   // 12.8 MB
  size_t w1t_o    = alloc((size_t)C1*F_IN*2);
  size_t w2t_o    = alloc((size_t)C2*C1*2);
  size_t wab_o    = alloc((size_t)32*F_IN*2);
  size_t asd_o    = alloc((size_t)N_NODES*32*4);     // 6.4 MB (src:0-11, dst:12-23)
  size_t h2_o     = alloc((size_t)N_NODES*C2*2);     // 6.4 MB
  size_t asrc2_o  = alloc((size_t)N_NODES*4);
  size_t adst2_o  = alloc((size_t)N_NODES*4);
  size_t walpha_o = alloc((size_t)ETOT*12*2);        // 20.4 MB bf16 unnormalized w
  size_t zero_beg = o;
  size_t counts_o = alloc((size_t)N_NODES*4);
  size_t pool_o   = alloc((size_t)G_GRAPHS*C2*4);
  size_t cnt_o    = alloc((size_t)G_GRAPHS*4);
  size_t zero_end = o;
  size_t rowptr_o = alloc((size_t)(N_NODES+1)*4);
  size_t bsum_o   = alloc((size_t)NBLK_SCAN*4);
  size_t cursor_o = alloc((size_t)N_NODES*4);
  size_t csr_o    = alloc((size_t)ETOT*4);
  size_t csrd_o   = alloc((size_t)ETOT*4);

  unsigned short* xb    = (unsigned short*)(ws + xb_o);
  unsigned short* w1t   = (unsigned short*)(ws + w1t_o);
  unsigned short* w2t   = (unsigned short*)(ws + w2t_o);
  unsigned short* wab   = (unsigned short*)(ws + wab_o);
  float* asd    = (float*)(ws + asd_o);
  unsigned short* h2b   = (unsigned short*)(ws + h2_o);
  float* asrc2  = (float*)(ws + asrc2_o);
  float* adst2  = (float*)(ws + adst2_o);
  unsigned short* walpha = (unsigned short*)(ws + walpha_o);
  int*   counts = (int*)  (ws + counts_o);
  float* poolf  = (float*)(ws + pool_o);
  int*   cnt    = (int*)  (ws + cnt_o);
  int*   rowptr = (int*)  (ws + rowptr_o);
  int*   bsum   = (int*)  (ws + bsum_o);
  int*   cursor = (int*)  (ws + cursor_o);
  int*   csrsrc = (int*)  (ws + csr_o);
  int*   csrdst = (int*)  (ws + csrd_o);

  hipMemsetAsync(ws + zero_beg, 0, zero_end - zero_beg, stream);

  const int TPB = 256;

  // prep
  prep_kernel<<<B_CAST + B_W1 + B_W2 + B_WAB, TPB, 0, stream>>>(
      x, W1, W2, att_src1, att_dst1, xb, w1t, w2t, wab);

  // CSR build
  count_cnt_kernel<<<EGRID + NGRID, TPB, 0, stream>>>(ei, batch, counts, cnt);
  scan_pass1<<<NBLK_SCAN, SCAN_B, 0, stream>>>(counts, rowptr, bsum);
  scan_pass3<<<(N_NODES + 1 + 255)/256, TPB, 0, stream>>>(rowptr, bsum, cursor);
  scatter_kernel<<<EGRID, TPB, 0, stream>>>(ei, cursor, csrsrc, csrdst);

  // conv1 logits
  gemm_mfma<64,32,32,16,true><<<dim3((N_NODES+63)/64, 1), 256, 0, stream>>>(xb, wab, asd, N_NODES, 32, F_IN);
  // per-edge conv1 weights (bf16, unnormalized, no-max)
  wprep_kernel<<<EGRID, TPB, 0, stream>>>(csrsrc, csrdst, asd, walpha);
  // conv1 agg + W1 + gemm2 + a2 grand fusion (deep-pipelined)
  agg1h_kernel<<<N_NODES/16, 512, 0, stream>>>(rowptr, csrsrc, xb, walpha, w1t, w2t,
                                               bias1, att_src2, att_dst2, h2b, asrc2, adst2);
  // conv2 aggregation + pool
  agg2s_kernel<<<(N_NODES+15)/16, TPB, 0, stream>>>(rowptr, csrsrc, h2b, asrc2, adst2, bias2, batch, poolf);

  // pool finalize
  finalize_kernel<<<(G_GRAPHS*C2 + TPB-1)/TPB, TPB, 0, stream>>>(poolf, cnt, out);
}

// Round 18
// 416.055 us; speedup vs baseline: 1.1276x; 1.1276x over previous
//
#include <hip/hip_runtime.h>

#define N_NODES 50000
#define N_EDGES 800000
#define ETOT (N_EDGES + N_NODES)   // 850000
#define G_GRAPHS 256
#define F_IN 128
#define H1 12
#define D1 32
#define C1 (H1*D1)   // 384
#define C2 64
#define NEG 0.2f
#define SCAN_B 1024
#define NBLK_SCAN ((N_NODES + SCAN_B - 1)/SCAN_B)   // 49

using bf16x8  = __attribute__((ext_vector_type(8))) short;
using ushort8 = __attribute__((ext_vector_type(8))) unsigned short;
using f32x4   = __attribute__((ext_vector_type(4))) float;

__device__ __forceinline__ float lrelu(float x){ return x > 0.f ? x : NEG*x; }
__device__ __forceinline__ unsigned short f2bf(float f){
  unsigned u = __float_as_uint(f);
  u += 0x7fffu + ((u >> 16) & 1u);
  return (unsigned short)(u >> 16);
}
__device__ __forceinline__ float bf2f(unsigned short h){
  return __uint_as_float(((unsigned)h) << 16);
}
// exp without max-subtraction; clamp is overflow guard only (never hit, |l|<=~8 here)
__device__ __forceinline__ float wexp(float l){ return __expf(fminf(l, 30.f)); }

// ---------- merged prep: cast x, transpose W1/W2, build wAb ----------
#define B_CAST ((N_NODES*F_IN/4 + 255)/256)   // 6250
#define B_W1   ((F_IN*C1 + 255)/256)          // 192
#define B_W2   ((C1*C2 + 255)/256)            // 96
#define B_WAB  ((32*F_IN + 255)/256)          // 16
__global__ void prep_kernel(const float* __restrict__ x, const float* __restrict__ W1,
    const float* __restrict__ W2, const float* __restrict__ att_src,
    const float* __restrict__ att_dst, unsigned short* __restrict__ xb,
    unsigned short* __restrict__ w1t, unsigned short* __restrict__ w2t,
    unsigned short* __restrict__ wAb){
  int b = blockIdx.x, tid = threadIdx.x;
  if (b < B_CAST){
    int base = (b*256 + tid)*4;
    if (base >= N_NODES*F_IN) return;
    float4 v = *(const float4*)(x + base);
    ushort4 o; o.x=f2bf(v.x); o.y=f2bf(v.y); o.z=f2bf(v.z); o.w=f2bf(v.w);
    *(ushort4*)(xb + base) = o;
  } else if (b < B_CAST + B_W1){
    int i = (b - B_CAST)*256 + tid;
    if (i >= F_IN*C1) return;
    int n = i / F_IN, k = i % F_IN;
    w1t[i] = f2bf(W1[(size_t)k*C1 + n]);
  } else if (b < B_CAST + B_W1 + B_W2){
    int i = (b - B_CAST - B_W1)*256 + tid;
    if (i >= C1*C2) return;
    int n = i / C1, k = i % C1;
    w2t[i] = f2bf(W2[(size_t)k*C2 + n]);
  } else {
    int i = (b - B_CAST - B_W1 - B_W2)*256 + tid;
    if (i >= 32*F_IN) return;
    int c = i >> 7, k = i & 127;
    float v = 0.f;
    if (c < 12){
      #pragma unroll
      for (int dd=0; dd<D1; ++dd) v += W1[(size_t)k*C1 + c*D1 + dd] * att_src[c*D1 + dd];
    } else if (c < 24){
      int h = c - 12;
      #pragma unroll
      for (int dd=0; dd<D1; ++dd) v += W1[(size_t)k*C1 + h*D1 + dd] * att_dst[h*D1 + dd];
    }
    wAb[i] = f2bf(v);
  }
}

// ---------- bf16 MFMA GEMM (logits): C[M][N] = A[M][K] @ Bt[N][K]^T ----------
template<int BM,int BN,int WM,int WN,bool F32OUT>
__global__ __launch_bounds__(256) void gemm_mfma(const unsigned short* __restrict__ A,
    const unsigned short* __restrict__ Bt, void* __restrict__ Cv,
    int M, int N, int K){
  constexpr int BK = 32;
  __shared__ unsigned short As2[4][BM][8];
  __shared__ unsigned short Bs2[4][BN][8];
  const int tid  = threadIdx.x;
  const int wid  = tid >> 6, lane = tid & 63;
  constexpr int NWX = BN / WN;
  const int wrow = (wid / NWX) * WM, wcol = (wid % NWX) * WN;
  constexpr int MR = WM/16, NR = WN/16;
  const int row0 = blockIdx.x * BM, col0 = blockIdx.y * BN;
  const int r = lane & 15, koct = lane >> 4;
  f32x4 acc[MR][NR];
  #pragma unroll
  for (int m=0;m<MR;m++)
    #pragma unroll
    for (int n=0;n<NR;n++) acc[m][n] = f32x4{0.f,0.f,0.f,0.f};

  for (int k0 = 0; k0 < K; k0 += BK){
    for (int s = tid; s < BM*8; s += 256){
      int rr = s >> 3, cc = (s & 7) * 4;
      int gr = row0 + rr;
      ushort4 v = (gr < M) ? *(const ushort4*)(A + (size_t)gr*K + k0 + cc)
                           : ushort4{0,0,0,0};
      *(ushort4*)(&As2[cc>>3][rr][cc&7]) = v;
    }
    for (int s = tid; s < BN*8; s += 256){
      int rr = s >> 3, cc = (s & 7) * 4;
      ushort4 v = *(const ushort4*)(Bt + (size_t)(col0+rr)*K + k0 + cc);
      *(ushort4*)(&Bs2[cc>>3][rr][cc&7]) = v;
    }
    __syncthreads();
    bf16x8 af[MR], bq[NR];
    #pragma unroll
    for (int m=0;m<MR;m++) af[m] = *(const bf16x8*)(&As2[koct][wrow + m*16 + r][0]);
    #pragma unroll
    for (int n=0;n<NR;n++) bq[n] = *(const bf16x8*)(&Bs2[koct][wcol + n*16 + r][0]);
    #pragma unroll
    for (int m=0;m<MR;m++)
      #pragma unroll
      for (int n=0;n<NR;n++)
        acc[m][n] = __builtin_amdgcn_mfma_f32_16x16x32_bf16(af[m], bq[n], acc[m][n], 0,0,0);
    __syncthreads();
  }
  #pragma unroll
  for (int m=0;m<MR;m++){
    #pragma unroll
    for (int rr=0; rr<4; rr++){
      int grow = row0 + wrow + m*16 + koct*4 + rr;
      if (grow < M){
        #pragma unroll
        for (int n=0;n<NR;n++){
          if constexpr (F32OUT)
            ((float*)Cv)[(size_t)grow*N + col0 + wcol + n*16 + r] = acc[m][n][rr];
          else
            ((unsigned short*)Cv)[(size_t)grow*N + col0 + wcol + n*16 + r] = f2bf(acc[m][n][rr]);
        }
      }
    }
  }
}

// ---------- CSR build ----------
#define EGRID ((ETOT + 255)/256)          // 3321
#define NGRID ((N_NODES + 255)/256)       // 196
__global__ void count_cnt_kernel(const int* __restrict__ ei, const int* __restrict__ batch,
                                 int* __restrict__ counts, int* __restrict__ cnt){
  if ((int)blockIdx.x < EGRID){
    int e = blockIdx.x*256 + threadIdx.x;
    if (e >= ETOT) return;
    int d = (e < N_EDGES) ? ei[N_EDGES + e] : (e - N_EDGES);
    atomicAdd(&counts[d], 1);
  } else {
    int n = (blockIdx.x - EGRID)*256 + threadIdx.x;
    if (n < N_NODES) atomicAdd(&cnt[batch[n]], 1);
  }
}
__global__ __launch_bounds__(SCAN_B) void scan_pass1(const int* __restrict__ counts,
    int* __restrict__ excl, int* __restrict__ bsum){
  __shared__ int sdata[SCAN_B];
  int i = blockIdx.x*SCAN_B + threadIdx.x;
  int v = (i < N_NODES) ? counts[i] : 0;
  sdata[threadIdx.x] = v;
  __syncthreads();
  for (int off=1; off<SCAN_B; off<<=1){
    int t = (threadIdx.x >= off) ? sdata[threadIdx.x-off] : 0;
    __syncthreads();
    sdata[threadIdx.x] += t;
    __syncthreads();
  }
  if (i < N_NODES) excl[i] = sdata[threadIdx.x] - v;
  if (threadIdx.x == SCAN_B-1) bsum[blockIdx.x] = sdata[SCAN_B-1];
}
__global__ void scan_pass3(int* __restrict__ rowptr, const int* __restrict__ bsum,
                           int* __restrict__ cursor){
  __shared__ int carry_s;
  int sblk = blockIdx.x >> 2;
  if (threadIdx.x == 0){
    int c = 0;
    for (int b=0; b<sblk; ++b) c += bsum[b];
    carry_s = c;
  }
  __syncthreads();
  int i = blockIdx.x*256 + (int)threadIdx.x;
  if (i < N_NODES){
    int r = rowptr[i] + carry_s;
    rowptr[i] = r; cursor[i] = r;
  }
  if (i == N_NODES) rowptr[N_NODES] = ETOT;
}
__global__ void scatter_kernel(const int* __restrict__ ei, int* __restrict__ cursor,
                               int* __restrict__ csr_src, int* __restrict__ csr_dst){
  int e = blockIdx.x*blockDim.x + threadIdx.x;
  if (e >= ETOT) return;
  int s, d;
  if (e < N_EDGES){ s = ei[e]; d = ei[N_EDGES + e]; } else { s = d = e - N_EDGES; }
  int slot = atomicAdd(&cursor[d], 1);
  csr_src[slot] = s;
  csr_dst[slot] = d;
}

// ---------- edge-parallel weight precompute: walpha[j][12] = bf16(exp(lrelu(aS+aD))) ----------
__global__ void wprep_kernel(const int* __restrict__ csr, const int* __restrict__ csrd,
                             const float* __restrict__ asd, unsigned short* __restrict__ walpha){
  int j = blockIdx.x*256 + threadIdx.x;
  if (j >= ETOT) return;
  int s = csr[j], d = csrd[j];
  float4 s0 = *(const float4*)(asd + (size_t)s*32);
  float4 s1 = *(const float4*)(asd + (size_t)s*32 + 4);
  float4 s2 = *(const float4*)(asd + (size_t)s*32 + 8);
  float4 d0 = *(const float4*)(asd + (size_t)d*32 + 12);
  float4 d1 = *(const float4*)(asd + (size_t)d*32 + 16);
  float4 d2 = *(const float4*)(asd + (size_t)d*32 + 20);
  float as[12] = {s0.x,s0.y,s0.z,s0.w, s1.x,s1.y,s1.z,s1.w, s2.x,s2.y,s2.z,s2.w};
  float ad[12] = {d0.x,d0.y,d0.z,d0.w, d1.x,d1.y,d1.z,d1.w, d2.x,d2.y,d2.z,d2.w};
  unsigned short wb[12];
  #pragma unroll
  for (int h=0;h<12;h++) wb[h] = f2bf(wexp(lrelu(as[h] + ad[h])));
  unsigned short* wp = walpha + (size_t)j*12;
  *(ushort4*)(wp)   = ushort4{wb[0],wb[1],wb[2],wb[3]};
  *(ushort4*)(wp+4) = ushort4{wb[4],wb[5],wb[6],wb[7]};
  *(ushort4*)(wp+8) = ushort4{wb[8],wb[9],wb[10],wb[11]};
}

// ---------- conv1 grand-fused: 32 lanes/dst, acc[12][4] (occupancy), chunk-32 staged w,
//            x-space agg + W1 MFMA + ReLU + gemm2 partials + a2. out1 never materialized.
// 512 thr = 8 waves = 16 dst/block (2 dst per wave).
__global__ __launch_bounds__(512, 4) void agg1h_kernel(const int* __restrict__ rowptr,
    const int* __restrict__ csr, const unsigned short* __restrict__ xb,
    const unsigned short* __restrict__ walpha, const unsigned short* __restrict__ w1t,
    const unsigned short* __restrict__ w2t, const float* __restrict__ bias1,
    const float* __restrict__ att_src2, const float* __restrict__ att_dst2,
    unsigned short* __restrict__ h2, float* __restrict__ asrc2, float* __restrict__ adst2){
  constexpr int ROWE = 6*F_IN + 8;            // 776 ushorts, per-slot agg row (6 heads)
  constexpr int WROW = 32*12 + 4;             // 388 floats, per-slot weight row (chunk 32)
  constexpr int ROWR = 192 + 8;               // 200 ushorts, relu-out1 half-row
  __shared__ unsigned short agg[16*ROWE];     // 24832 B  (aliased: red at end)
  __shared__ float wlds[16][WROW];            // 24832 B  (aliased: reluLDS in epilogue)

  unsigned short* reluLDS = (unsigned short*)&wlds[0][0];   // 16 x ROWR ushorts = 6400 B
  float* red = (float*)&agg[0];                              // a2 reduce scratch

  const int tid  = threadIdx.x;
  const int wv   = tid >> 6;                  // wave 0..7
  const int lane = tid & 63;
  const int half = lane >> 5;                 // which dst of the wave's pair
  const int t32  = lane & 31;                 // lane within dst (4 feats each)
  const int base = lane & 32;                 // wave-lane base of this 32-lane group
  const int slot = wv*2 + half;               // 0..15 dst in block
  const int d    = blockIdx.x*16 + slot;
  const int r0 = rowptr[d], r1 = rowptr[d+1];

  float acc[12][4];
  #pragma unroll
  for (int h=0;h<12;h++)
    #pragma unroll
    for (int i=0;i<4;i++) acc[h][i] = 0.f;
  float ss[12];
  #pragma unroll
  for (int h=0;h<12;h++) ss[h] = 0.f;

  // ---- main loop: 32-edge chunks; all 32 lanes stage (csr reg + w -> LDS) ----
  for (int c0 = r0; c0 < r1; c0 += 32){
    int nc = min(32, r1 - c0);
    int s_st = 0;
    if (t32 < nc){
      int j = c0 + t32;
      s_st = csr[j];
      const unsigned short* wp = walpha + (size_t)j*12;
      ushort4 u0 = *(const ushort4*)(wp);
      ushort4 u1 = *(const ushort4*)(wp+4);
      ushort4 u2 = *(const ushort4*)(wp+8);
      float w[12] = {bf2f(u0.x),bf2f(u0.y),bf2f(u0.z),bf2f(u0.w),
                     bf2f(u1.x),bf2f(u1.y),bf2f(u1.z),bf2f(u1.w),
                     bf2f(u2.x),bf2f(u2.y),bf2f(u2.z),bf2f(u2.w)};
      #pragma unroll
      for (int h=0;h<12;h++) ss[h] += w[h];
      *(float4*)(&wlds[slot][t32*12 + 0]) = float4{w[0],w[1],w[2],w[3]};
      *(float4*)(&wlds[slot][t32*12 + 4]) = float4{w[4],w[5],w[6],w[7]};
      *(float4*)(&wlds[slot][t32*12 + 8]) = float4{w[8],w[9],w[10],w[11]};
    }
    __builtin_amdgcn_wave_barrier();
    // 3-deep x prefetch (ushort4 per lane; 32 lanes cover the 256B row)
    int sA = __shfl(s_st, base + 0);
    ushort4 xA = *(const ushort4*)(xb + (size_t)sA*F_IN + t32*4);
    ushort4 xB = {0,0,0,0}, xC = {0,0,0,0};
    if (nc > 1){
      int sB = __shfl(s_st, base + 1);
      xB = *(const ushort4*)(xb + (size_t)sB*F_IN + t32*4);
    }
    if (nc > 2){
      int sC = __shfl(s_st, base + 2);
      xC = *(const ushort4*)(xb + (size_t)sC*F_IN + t32*4);
    }
    for (int e = 0; e < nc; ++e){
      ushort4 cx = xA;
      xA = xB; xB = xC;
      if (e + 3 < nc){
        int sN = __shfl(s_st, base + e + 3);
        xC = *(const ushort4*)(xb + (size_t)sN*F_IN + t32*4);
      }
      float4 w0 = *(const float4*)(&wlds[slot][e*12 + 0]);
      float4 w1 = *(const float4*)(&wlds[slot][e*12 + 4]);
      float4 w2 = *(const float4*)(&wlds[slot][e*12 + 8]);
      float xf[4] = {bf2f(cx.x), bf2f(cx.y), bf2f(cx.z), bf2f(cx.w)};
      float w[12] = {w0.x,w0.y,w0.z,w0.w, w1.x,w1.y,w1.z,w1.w, w2.x,w2.y,w2.z,w2.w};
      #pragma unroll
      for (int h=0;h<12;h++)
        #pragma unroll
        for (int i=0;i<4;i++) acc[h][i] += w[h]*xf[i];
    }
    __builtin_amdgcn_wave_barrier();
  }

  // reduce ss over 32-lane group; normalize factors
  #pragma unroll
  for (int h=0;h<12;h++){
    #pragma unroll
    for (int off=16; off; off>>=1) ss[h] += __shfl_xor(ss[h], off);
  }
  float inv[12];
  #pragma unroll
  for (int h=0;h<12;h++) inv[h] = 1.f / ss[h];

  // ---- epilogue: per 6-head half: agg->LDS, W1-MFMA + bias + ReLU -> reluLDS,
  //      then partial gemm2 (K=192) accumulating h2 in regs ----
  const int er = lane & 15, eq = lane >> 4;
  f32x4 h2acc = {0.f,0.f,0.f,0.f};
  #pragma unroll
  for (int hf = 0; hf < 2; ++hf){
    __syncthreads();   // main loop done (hf=0) / prev half's reluLDS+agg reads done (hf=1)
    #pragma unroll
    for (int h = 0; h < 6; ++h){
      int hh = hf*6 + h;
      ushort4 v;
      v.x = f2bf(acc[hh][0]*inv[hh]); v.y = f2bf(acc[hh][1]*inv[hh]);
      v.z = f2bf(acc[hh][2]*inv[hh]); v.w = f2bf(acc[hh][3]*inv[hh]);
      *(ushort4*)(&agg[slot*ROWE + h*F_IN + t32*4]) = v;
    }
    __syncthreads();
    // W1 transform: 12 tiles (192 cols this half) over 8 waves
    for (int tt = wv; tt < 12; tt += 8){
      int h = tt >> 1, nb = tt & 1;
      int hh = hf*6 + h;
      f32x4 c = {0.f,0.f,0.f,0.f};
      #pragma unroll
      for (int kk=0; kk<4; ++kk){
        bf16x8 af = *(const bf16x8*)(&agg[er*ROWE + h*F_IN + kk*32 + eq*8]);
        bf16x8 bq = *(const bf16x8*)(w1t + (size_t)(hh*32 + nb*16 + er)*F_IN + kk*32 + eq*8);
        c = __builtin_amdgcn_mfma_f32_16x16x32_bf16(af, bq, c, 0,0,0);
      }
      int lcol = tt*16 + er;                    // local col within half (0..191)
      float bv = bias1[hf*192 + lcol];
      #pragma unroll
      for (int rr=0; rr<4; ++rr){
        int row = eq*4 + rr;                    // dst row 0..15
        reluLDS[row*ROWR + lcol] = f2bf(fmaxf(c[rr] + bv, 0.f));
      }
    }
    __syncthreads();
    // partial gemm2: waves 0..3 own h2 cols [wv*16, wv*16+16), K=192 this half
    if (wv < 4){
      #pragma unroll
      for (int kk=0; kk<6; ++kk){
        bf16x8 af = *(const bf16x8*)(&reluLDS[er*ROWR + kk*32 + eq*8]);
        bf16x8 bq = *(const bf16x8*)(w2t + (size_t)(wv*16 + er)*C1 + hf*192 + kk*32 + eq*8);
        h2acc = __builtin_amdgcn_mfma_f32_16x16x32_bf16(af, bq, h2acc, 0,0,0);
      }
    }
  }
  __syncthreads();   // reluLDS/agg reads done; agg region reusable as red

  // ---- write h2 (bf16) + a2 dots (waves 0..3) ----
  if (wv < 4){
    float attS = att_src2[wv*16 + er];
    float attD = att_dst2[wv*16 + er];
    float psum[4], pdum[4];
    #pragma unroll
    for (int rr=0; rr<4; ++rr){
      int row = eq*4 + rr;
      int gn = blockIdx.x*16 + row;
      h2[(size_t)gn*C2 + wv*16 + er] = f2bf(h2acc[rr]);
      psum[rr] = h2acc[rr]*attS;
      pdum[rr] = h2acc[rr]*attD;
    }
    #pragma unroll
    for (int rr=0; rr<4; ++rr){
      #pragma unroll
      for (int off=8; off; off>>=1){
        psum[rr] += __shfl_xor(psum[rr], off);
        pdum[rr] += __shfl_xor(pdum[rr], off);
      }
    }
    if (er == 0){
      #pragma unroll
      for (int rr=0; rr<4; ++rr){
        int row = eq*4 + rr;
        red[(wv*16 + row)*2 + 0] = psum[rr];
        red[(wv*16 + row)*2 + 1] = pdum[rr];
      }
    }
  }
  __syncthreads();
  if (tid < 32){
    int row = tid >> 1, which = tid & 1;
    float v = red[row*2+which] + red[(16+row)*2+which] + red[(32+row)*2+which] + red[(48+row)*2+which];
    int gn = blockIdx.x*16 + row;
    if (which == 0) asrc2[gn] = v; else adst2[gn] = v;
  }
}

// ---------- conv2: no-max softmax + aggregation + pool atomics ----------
__global__ __launch_bounds__(256) void agg2s_kernel(const int* __restrict__ rowptr,
    const int* __restrict__ csr, const unsigned short* __restrict__ h2,
    const float* __restrict__ asrc, const float* __restrict__ adst,
    const float* __restrict__ bias, const int* __restrict__ batch,
    float* __restrict__ pool){
  const int tid  = threadIdx.x;
  const int slot = tid >> 4;
  const int t16  = tid & 15;
  const int base = ((tid & 63) >> 4) * 16;
  const int d    = blockIdx.x*16 + slot;
  const int r0 = rowptr[d], r1 = rowptr[d+1];
  const float ad = adst[d];

  float ssp = 0.f;
  float a0=0.f, a1=0.f, a2=0.f, a3=0.f;

  for (int c0 = r0; c0 < r1; c0 += 16){
    int nc = min(16, r1 - c0);
    int s_st = 0; float w_st = 0.f;
    if (t16 < nc){
      s_st = csr[c0 + t16];
      w_st = wexp(lrelu(asrc[s_st] + ad));
      ssp += w_st;
    }
    int sA = __shfl(s_st, base + 0);
    ushort4 xA = *(const ushort4*)(h2 + (size_t)sA*C2 + t16*4);
    ushort4 xB = {0,0,0,0}, xC = {0,0,0,0};
    if (nc > 1){
      int sB = __shfl(s_st, base + 1);
      xB = *(const ushort4*)(h2 + (size_t)sB*C2 + t16*4);
    }
    if (nc > 2){
      int sC = __shfl(s_st, base + 2);
      xC = *(const ushort4*)(h2 + (size_t)sC*C2 + t16*4);
    }
    for (int e = 0; e < nc; ++e){
      ushort4 cx = xA;
      xA = xB; xB = xC;
      if (e + 3 < nc){
        int sN = __shfl(s_st, base + e + 3);
        xC = *(const ushort4*)(h2 + (size_t)sN*C2 + t16*4);
      }
      float w = __shfl(w_st, base + e);
      a0 += w*bf2f(cx.x);
      a1 += w*bf2f(cx.y);
      a2 += w*bf2f(cx.z);
      a3 += w*bf2f(cx.w);
    }
  }
  #pragma unroll
  for (int off=8; off; off>>=1) ssp += __shfl_xor(ssp, off);
  float inv = 1.f / ssp;
  int g = batch[d];
  int fb = t16*4;
  atomicAdd(&pool[g*C2 + fb+0], a0*inv + bias[fb+0]);
  atomicAdd(&pool[g*C2 + fb+1], a1*inv + bias[fb+1]);
  atomicAdd(&pool[g*C2 + fb+2], a2*inv + bias[fb+2]);
  atomicAdd(&pool[g*C2 + fb+3], a3*inv + bias[fb+3]);
}

__global__ void finalize_kernel(const float* __restrict__ sums, const int* __restrict__ cnt,
                                float* __restrict__ out){
  int i = blockIdx.x*blockDim.x + threadIdx.x;
  if (i >= G_GRAPHS*C2) return;
  int g = i >> 6;
  out[i] = sums[i] / fmaxf((float)cnt[g], 1.f);
}

// ---------- launch ----------
extern "C" void kernel_launch(void* const* d_in, const int* in_sizes, int n_in,
                              void* d_out, int out_size, void* d_ws, size_t ws_size,
                              hipStream_t stream) {
  const float* x        = (const float*)d_in[0];
  const int*   ei       = (const int*)  d_in[1];
  const int*   batch    = (const int*)  d_in[2];
  const float* W1       = (const float*)d_in[3];
  const float* att_src1 = (const float*)d_in[4];
  const float* att_dst1 = (const float*)d_in[5];
  const float* bias1    = (const float*)d_in[6];
  const float* W2       = (const float*)d_in[7];
  const float* att_src2 = (const float*)d_in[8];
  const float* att_dst2 = (const float*)d_in[9];
  const float* bias2    = (const float*)d_in[10];
  float* out = (float*)d_out;

  char* ws = (char*)d_ws;
  size_t o = 0;
  auto alloc = [&](size_t bytes)->size_t{ size_t r=o; o=(o+bytes+255)&~(size_t)255; return r; };

  size_t xb_o     = alloc((size_t)N_NODES*F_IN*2);   // 12.8 MB
  size_t w1t_o    = alloc((size_t)C1*F_IN*2);
  size_t w2t_o    = alloc((size_t)C2*C1*2);
  size_t wab_o    = alloc((size_t)32*F_IN*2);
  size_t asd_o    = alloc((size_t)N_NODES*32*4);     // 6.4 MB (src:0-11, dst:12-23)
  size_t h2_o     = alloc((size_t)N_NODES*C2*2);     // 6.4 MB
  size_t asrc2_o  = alloc((size_t)N_NODES*4);
  size_t adst2_o  = alloc((size_t)N_NODES*4);
  size_t walpha_o = alloc((size_t)ETOT*12*2);        // 20.4 MB bf16 unnormalized w
  size_t zero_beg = o;
  size_t counts_o = alloc((size_t)N_NODES*4);
  size_t pool_o   = alloc((size_t)G_GRAPHS*C2*4);
  size_t cnt_o    = alloc((size_t)G_GRAPHS*4);
  size_t zero_end = o;
  size_t rowptr_o = alloc((size_t)(N_NODES+1)*4);
  size_t bsum_o   = alloc((size_t)NBLK_SCAN*4);
  size_t cursor_o = alloc((size_t)N_NODES*4);
  size_t csr_o    = alloc((size_t)ETOT*4);
  size_t csrd_o   = alloc((size_t)ETOT*4);

  unsigned short* xb    = (unsigned short*)(ws + xb_o);
  unsigned short* w1t   = (unsigned short*)(ws + w1t_o);
  unsigned short* w2t   = (unsigned short*)(ws + w2t_o);
  unsigned short* wab   = (unsigned short*)(ws + wab_o);
  float* asd    = (float*)(ws + asd_o);
  unsigned short* h2b   = (unsigned short*)(ws + h2_o);
  float* asrc2  = (float*)(ws + asrc2_o);
  float* adst2  = (float*)(ws + adst2_o);
  unsigned short* walpha = (unsigned short*)(ws + walpha_o);
  int*   counts = (int*)  (ws + counts_o);
  float* poolf  = (float*)(ws + pool_o);
  int*   cnt    = (int*)  (ws + cnt_o);
  int*   rowptr = (int*)  (ws + rowptr_o);
  int*   bsum   = (int*)  (ws + bsum_o);
  int*   cursor = (int*)  (ws + cursor_o);
  int*   csrsrc = (int*)  (ws + csr_o);
  int*   csrdst = (int*)  (ws + csrd_o);

  hipMemsetAsync(ws + zero_beg, 0, zero_end - zero_beg, stream);

  const int TPB = 256;

  // prep
  prep_kernel<<<B_CAST + B_W1 + B_W2 + B_WAB, TPB, 0, stream>>>(
      x, W1, W2, att_src1, att_dst1, xb, w1t, w2t, wab);

  // CSR build
  count_cnt_kernel<<<EGRID + NGRID, TPB, 0, stream>>>(ei, batch, counts, cnt);
  scan_pass1<<<NBLK_SCAN, SCAN_B, 0, stream>>>(counts, rowptr, bsum);
  scan_pass3<<<(N_NODES + 1 + 255)/256, TPB, 0, stream>>>(rowptr, bsum, cursor);
  scatter_kernel<<<EGRID, TPB, 0, stream>>>(ei, cursor, csrsrc, csrdst);

  // conv1 logits
  gemm_mfma<64,32,32,16,true><<<dim3((N_NODES+63)/64, 1), 256, 0, stream>>>(xb, wab, asd, N_NODES, 32, F_IN);
  // per-edge conv1 weights (bf16, unnormalized, no-max)
  wprep_kernel<<<EGRID, TPB, 0, stream>>>(csrsrc, csrdst, asd, walpha);
  // conv1 agg + W1 + gemm2 + a2 grand fusion (32 lanes/dst)
  agg1h_kernel<<<N_NODES/16, 512, 0, stream>>>(rowptr, csrsrc, xb, walpha, w1t, w2t,
                                               bias1, att_src2, att_dst2, h2b, asrc2, adst2);
  // conv2 aggregation + pool
  agg2s_kernel<<<(N_NODES+15)/16, TPB, 0, stream>>>(rowptr, csrsrc, h2b, asrc2, adst2, bias2, batch, poolf);

  // pool finalize
  finalize_kernel<<<(G_GRAPHS*C2 + TPB-1)/TPB, TPB, 0, stream>>>(poolf, cnt, out);
}